// Round 2
// baseline (170.539 us; speedup 1.0000x reference)
//
#include <hip/hip_runtime.h>
#include <math.h>

// Geometry fixed by setup_inputs()
#define NB 16
#define NT 50
#define NA 3
#define NG 76
#define NCELL (NG*NG)             // 5776
#define NCH 255                   // 3*(5+80)
#define TOT (NB*NA*NCELL)         // 277248
#define MASKWORDS ((TOT+31)/32)   // 8664
#define ZEROWORDS ((NCELL+31)/32) // 181
#define BBLOCKS ((TOT+255)/256)   // 1083

static_assert(TOT == 277248, "geometry");

__device__ __forceinline__ float sigmoidf_(float v) { return 1.0f / (1.0f + expf(-v)); }

// ---------------------------------------------------------------------------
// Kernel A (1 block, 1024 threads):
//  - zero the bitmaps + accumulators (ws is 0xAA-poisoned every launch)
//  - per (b,t): rep(), grid coords, per-anchor IoU -> best anchor + ignore bit
//  - last-write-wins winner resolution via in-LDS key scan (matches np
//    sequential scatter order: largest t with the same (b,best,gj,gi) wins)
//  - winners gather their cell's 5 prediction values and block-reduce the
//    six target-side sums: [0..3] masked MSE x/y/w/h, [4] obj BCE, [5] n_mask
// ---------------------------------------------------------------------------
__global__ __launch_bounds__(1024) void yolo_prep(
    const float* __restrict__ sample,
    const float* __restrict__ targets,
    const float* __restrict__ anchors,
    unsigned* __restrict__ maskbits,
    unsigned* __restrict__ zerobits,
    double* __restrict__ sums,       // [8]: 0..5 target-side, 6..7 noobj (zeroed here)
    int* __restrict__ counter)
{
    const int tid = threadIdx.x;

    for (int i = tid; i < MASKWORDS; i += 1024) maskbits[i] = 0u;
    for (int i = tid; i < ZEROWORDS; i += 1024) zerobits[i] = 0u;
    if (tid < 2) sums[6 + tid] = 0.0;
    if (tid == 0) *counter = 0;

    __shared__ int keys[NB * NT];

    const bool active = tid < NB * NT;
    int key = -1, cell = 0, b = 0, best = 0, gi = 0, gj = 0;
    float gx = 0, gy = 0, gw = 0, gh = 0;
    bool ign = false;

    if (active) {
        b = tid / NT;
        const int t = tid % NT;
        const float* T  = targets + (size_t)(b * NT + t) * 5;
        const float* T0 = targets + (size_t)(b * NT) * 5;
        const float s = T[0] + T[1] + T[2] + T[3] + T[4];
        const float* U = (s > 0.0f) ? T : T0;   // rep(): invalid rows use row 0
        gx = U[1] * (float)NG; gy = U[2] * (float)NG;
        gw = U[3] * (float)NG; gh = U[4] * (float)NG;
        gi = (int)gx; gj = (int)gy;             // coords > 0, trunc == astype(int32)
        float bi = -1e30f;
#pragma unroll
        for (int a = 0; a < NA; ++a) {
            const float aw = anchors[2 * a + 0] * 0.125f;  // /stride, stride=8
            const float ah = anchors[2 * a + 1] * 0.125f;
            const float inter = fmaxf(fminf(gw, aw) + 1.0f, 0.0f) *
                                fmaxf(fminf(gh, ah) + 1.0f, 0.0f);
            const float den = (gw + 1.0f) * (gh + 1.0f) +
                              (aw + 1.0f) * (ah + 1.0f) - inter + 1e-12f;
            const float iou = inter / den;
            if (iou > 0.5f) ign = true;                 // IGNORE_THRES (any anchor)
            if (iou > bi) { bi = iou; best = a; }       // strict > == first-max argmax
        }
        cell = gj * NG + gi;
        key  = ((b * NA + best) * NG + gj) * NG + gi;   // linear (b,a,j,i) index
        keys[tid] = key;
    }
    __syncthreads();   // bitmaps zeroed + keys visible

    double acc[6] = {0, 0, 0, 0, 0, 0};
    if (active) {
        if (ign) atomicOr(&zerobits[cell >> 5], 1u << (cell & 31));
        const int t = tid % NT;
        bool win = true;
        for (int t2 = t + 1; t2 < NT; ++t2)
            if (keys[b * NT + t2] == key) { win = false; break; }
        if (win) {
            atomicOr(&maskbits[key >> 5], 1u << (key & 31));
            const float* S = sample + ((size_t)(b * NCH + best * 85)) * NCELL + cell;
            const float px = S[0 * NCELL];
            const float py = S[1 * NCELL];
            const float pw = S[2 * NCELL];
            const float ph = S[3 * NCELL];
            const float pc = S[4 * NCELL];
            const float aw = anchors[2 * best + 0] * 0.125f;
            const float ah = anchors[2 * best + 1] * 0.125f;
            const float tx = gx - (float)gi;
            const float ty = gy - (float)gj;
            const float tw = logf(gw / aw + 1e-16f);
            const float th = logf(gh / ah + 1e-16f);
            const float x = sigmoidf_(px), y = sigmoidf_(py);
            const float conf = sigmoidf_(pc);
            acc[0] = (double)((x - tx) * (x - tx));
            acc[1] = (double)((y - ty) * (y - ty));
            acc[2] = (double)((pw - tw) * (pw - tw));
            acc[3] = (double)((ph - th) * (ph - th));
            acc[4] = -(double)logf(conf + 1e-12f);      // obj BCE, t=1
            acc[5] = 1.0;                               // n_mask
        }
    }

    // block reduce 6 doubles across 16 waves
#pragma unroll
    for (int k = 0; k < 6; ++k) {
        double v = acc[k];
#pragma unroll
        for (int o = 32; o > 0; o >>= 1) v += __shfl_down(v, o, 64);
        acc[k] = v;
    }
    __shared__ double sred[16][6];
    const int lane = tid & 63, wid = tid >> 6;
    if (lane == 0) {
#pragma unroll
        for (int k = 0; k < 6; ++k) sred[wid][k] = acc[k];
    }
    __syncthreads();
    if (tid == 0) {
#pragma unroll
        for (int k = 0; k < 6; ++k) {
            double v = 0.0;
#pragma unroll
            for (int w = 0; w < 16; ++w) v += sred[w][k];
            sums[k] = v;
        }
    }
}

// ---------------------------------------------------------------------------
// Kernel B: noobj BCE over all cells (conf channel only) + last-block finalize.
// cm_false[b,a,j,i] = (1 - mask[b,a,j,i]) * (cell_zero[j,i] ? 0 : 1)
// ---------------------------------------------------------------------------
__global__ __launch_bounds__(256) void yolo_noobj(
    const float* __restrict__ sample,
    const unsigned* __restrict__ maskbits,
    const unsigned* __restrict__ zerobits,
    double* __restrict__ sums,
    int* __restrict__ counter,
    float* __restrict__ out)
{
    const int idx = blockIdx.x * 256 + threadIdx.x;
    double sn = 0.0, cn = 0.0;
    if (idx < TOT) {
        const int cell = idx % NCELL;
        const bool m = (maskbits[idx >> 5]  >> (idx  & 31)) & 1u;
        const bool z = (zerobits[cell >> 5] >> (cell & 31)) & 1u;
        if (!m && !z) {
            const int b = idx / (NA * NCELL);
            const int a = (idx / NCELL) % NA;
            const float pc = sample[((size_t)(b * NCH + a * 85 + 4)) * NCELL + cell];
            const float conf = sigmoidf_(pc);
            sn = -(double)logf(1.0f - conf + 1e-12f);   // noobj BCE, t=0
            cn = 1.0;
        }
    }

    // block reduce 2 doubles
#pragma unroll
    for (int o = 32; o > 0; o >>= 1) {
        sn += __shfl_down(sn, o, 64);
        cn += __shfl_down(cn, o, 64);
    }
    __shared__ double sr[4][2];
    const int lane = threadIdx.x & 63, wid = threadIdx.x >> 6;
    if (lane == 0) { sr[wid][0] = sn; sr[wid][1] = cn; }
    __syncthreads();

    if (threadIdx.x == 0) {
        const double S = sr[0][0] + sr[1][0] + sr[2][0] + sr[3][0];
        const double C = sr[0][1] + sr[1][1] + sr[2][1] + sr[3][1];
        atomicAdd(&sums[6], S);
        atomicAdd(&sums[7], C);
        __threadfence();
        const int old = atomicAdd(counter, 1);
        if (old == BBLOCKS - 1) {
            // last block: all other blocks' adds are fenced + visible
            double r[8];
#pragma unroll
            for (int k = 0; k < 8; ++k) r[k] = atomicAdd(&sums[k], 0.0); // coherent read
            const double nm = fmax(r[5], 1.0);   // max(sum(mask),1)
            const double nn = fmax(r[7], 1.0);   // max(sum(cm_false),1)
            const double lx = 2.0 * r[0] / nm;   // XY_LOSS
            const double ly = 2.0 * r[1] / nm;
            const double lw = 1.6 * r[2] / nm;   // WH_LOSS
            const double lh = 1.6 * r[3] / nm;
            const double lobj   = r[4] / nm;     // OBJ_LOSS
            const double lnoobj = 0.5 * r[6] / nn; // NOOBJ_LOSS
            out[0] = (float)(lx + ly + lw + lh + lnoobj + lobj);
            out[1] = (float)lx;
            out[2] = (float)ly;
            out[3] = (float)lw;
            out[4] = (float)lh;
            out[5] = (float)lobj;
            out[6] = (float)lnoobj;
        }
    }
}

// ---------------------------------------------------------------------------
extern "C" void kernel_launch(void* const* d_in, const int* in_sizes, int n_in,
                              void* d_out, int out_size, void* d_ws, size_t ws_size,
                              hipStream_t stream)
{
    const float* sample  = (const float*)d_in[0];   // (16,255,76,76) f32
    const float* targets = (const float*)d_in[1];   // (16,50,5) f32
    const float* anchors = (const float*)d_in[2];   // (3,2) f32
    float* out = (float*)d_out;                     // 7 f32

    char* ws = (char*)d_ws;
    unsigned* maskbits = (unsigned*)ws;                       // 8664 words
    unsigned* zerobits = (unsigned*)(ws + 34656);             // 181 words
    double*   sums     = (double*)(ws + 35392);               // 8 doubles (64B-aligned)
    int*      counter  = (int*)(ws + 35392 + 64);

    yolo_prep<<<1, 1024, 0, stream>>>(sample, targets, anchors,
                                      maskbits, zerobits, sums, counter);
    yolo_noobj<<<BBLOCKS, 256, 0, stream>>>(sample, maskbits, zerobits,
                                            sums, counter, out);
}

// Round 3
// 136.793 us; speedup vs baseline: 1.2467x; 1.2467x over previous
//
#include <hip/hip_runtime.h>
#include <math.h>

// Geometry fixed by setup_inputs()
#define NB 16
#define NT 50
#define NA 3
#define NG 76
#define NCELL (NG*NG)             // 5776
#define NCH 255                   // 3*(5+80)
#define TOT (NB*NA*NCELL)         // 277248
#define MASKWORDS ((TOT+31)/32)   // 8664
#define ZEROWORDS ((NCELL+31)/32) // 181
#define NPLANES (NB*NA)           // 48 conf planes
#define F4PP (NCELL/4)            // 1444 float4 per plane
#define QPP 4                     // quarters per plane
#define F4PQ (F4PP/QPP)           // 361 float4 per quarter
#define NBLK_B (NPLANES*QPP)      // 192 blocks

static_assert(TOT == 277248, "geometry");
static_assert(F4PP * 4 == NCELL, "vec4");

__device__ __forceinline__ float sigmoidf_(float v) { return 1.0f / (1.0f + expf(-v)); }

// ---------------------------------------------------------------------------
// Kernel A (1 block, 1024 threads):
//  - zero bitmaps + counter (ws is 0xAA-poisoned before every launch)
//  - per (b,t): rep(), grid coords, per-anchor IoU -> best anchor + ignore bit
//  - last-write-wins winner via in-LDS key scan (largest t with same key wins,
//    matching np sequential scatter order)
//  - winners gather their cell's 5 prediction values; block-reduce the six
//    target-side sums: [0..3] masked MSE x/y/w/h, [4] obj BCE, [5] n_mask
// ---------------------------------------------------------------------------
__global__ __launch_bounds__(1024) void yolo_prep(
    const float* __restrict__ sample,
    const float* __restrict__ targets,
    const float* __restrict__ anchors,
    unsigned* __restrict__ maskbits,
    unsigned* __restrict__ zerobits,
    double* __restrict__ sums,       // [6] target-side sums
    int* __restrict__ counter)
{
    const int tid = threadIdx.x;

    for (int i = tid; i < MASKWORDS; i += 1024) maskbits[i] = 0u;
    for (int i = tid; i < ZEROWORDS; i += 1024) zerobits[i] = 0u;
    if (tid == 0) *counter = 0;

    __shared__ int keys[NB * NT];

    const bool active = tid < NB * NT;
    int key = -1, cell = 0, b = 0, best = 0, gi = 0, gj = 0;
    float gx = 0, gy = 0, gw = 0, gh = 0;
    bool ign = false;

    if (active) {
        b = tid / NT;
        const int t = tid % NT;
        const float* T  = targets + (size_t)(b * NT + t) * 5;
        const float* T0 = targets + (size_t)(b * NT) * 5;
        const float s = T[0] + T[1] + T[2] + T[3] + T[4];
        const float* U = (s > 0.0f) ? T : T0;   // rep(): invalid rows use row 0
        gx = U[1] * (float)NG; gy = U[2] * (float)NG;
        gw = U[3] * (float)NG; gh = U[4] * (float)NG;
        gi = (int)gx; gj = (int)gy;             // coords > 0: trunc == astype(int32)
        float bi = -1e30f;
#pragma unroll
        for (int a = 0; a < NA; ++a) {
            const float aw = anchors[2 * a + 0] * 0.125f;  // /stride, stride=8
            const float ah = anchors[2 * a + 1] * 0.125f;
            const float inter = fmaxf(fminf(gw, aw) + 1.0f, 0.0f) *
                                fmaxf(fminf(gh, ah) + 1.0f, 0.0f);
            const float den = (gw + 1.0f) * (gh + 1.0f) +
                              (aw + 1.0f) * (ah + 1.0f) - inter + 1e-12f;
            const float iou = inter / den;
            if (iou > 0.5f) ign = true;                 // IGNORE_THRES (any anchor)
            if (iou > bi) { bi = iou; best = a; }       // strict > == first-max argmax
        }
        cell = gj * NG + gi;
        key  = ((b * NA + best) * NG + gj) * NG + gi;   // linear (b,a,j,i)
        keys[tid] = key;
    }
    __syncthreads();   // bitmaps zeroed + keys visible

    double acc[6] = {0, 0, 0, 0, 0, 0};
    if (active) {
        if (ign) atomicOr(&zerobits[cell >> 5], 1u << (cell & 31));
        const int t = tid % NT;
        bool win = true;
        for (int t2 = t + 1; t2 < NT; ++t2)
            if (keys[b * NT + t2] == key) { win = false; break; }
        if (win) {
            atomicOr(&maskbits[key >> 5], 1u << (key & 31));
            const float* S = sample + ((size_t)(b * NCH + best * 85)) * NCELL + cell;
            const float px = S[0 * NCELL];
            const float py = S[1 * NCELL];
            const float pw = S[2 * NCELL];
            const float ph = S[3 * NCELL];
            const float pc = S[4 * NCELL];
            const float aw = anchors[2 * best + 0] * 0.125f;
            const float ah = anchors[2 * best + 1] * 0.125f;
            const float tx = gx - (float)gi;
            const float ty = gy - (float)gj;
            const float tw = logf(gw / aw + 1e-16f);
            const float th = logf(gh / ah + 1e-16f);
            const float x = sigmoidf_(px), y = sigmoidf_(py);
            const float conf = sigmoidf_(pc);
            acc[0] = (double)((x - tx) * (x - tx));
            acc[1] = (double)((y - ty) * (y - ty));
            acc[2] = (double)((pw - tw) * (pw - tw));
            acc[3] = (double)((ph - th) * (ph - th));
            acc[4] = -(double)logf(conf + 1e-12f);      // obj BCE, t=1
            acc[5] = 1.0;                               // n_mask
        }
    }

#pragma unroll
    for (int k = 0; k < 6; ++k) {
        double v = acc[k];
#pragma unroll
        for (int o = 32; o > 0; o >>= 1) v += __shfl_down(v, o, 64);
        acc[k] = v;
    }
    __shared__ double sred[16][6];
    const int lane = tid & 63, wid = tid >> 6;
    if (lane == 0) {
#pragma unroll
        for (int k = 0; k < 6; ++k) sred[wid][k] = acc[k];
    }
    __syncthreads();
    if (tid == 0) {
#pragma unroll
        for (int k = 0; k < 6; ++k) {
            double v = 0.0;
#pragma unroll
            for (int w = 0; w < 16; ++w) v += sred[w][k];
            sums[k] = v;
        }
    }
}

// ---------------------------------------------------------------------------
// Kernel B: noobj BCE over all cells, conf channel only, float4 loads.
// cm_false[b,a,j,i] = (1 - mask) * (1 - cell_zero). Per-block partials
// (contention-free), counter-gated last-block finalize.
// ---------------------------------------------------------------------------
__global__ __launch_bounds__(256) void yolo_noobj(
    const float* __restrict__ sample,
    const unsigned* __restrict__ maskbits,
    const unsigned* __restrict__ zerobits,
    const double* __restrict__ sums,       // [6] from kernel A
    double* __restrict__ partials,         // [NBLK_B][2]
    int* __restrict__ counter,
    float* __restrict__ out)
{
    const int p = blockIdx.x / QPP;        // plane = b*NA + a
    const int q = blockIdx.x % QPP;        // quarter within plane
    const int b = p / NA, a = p % NA;
    const float4* conf4 =
        (const float4*)(sample + ((size_t)(b * NCH + a * 85 + 4)) * NCELL);

    double sn = 0.0, cn = 0.0;
    for (int j = q * F4PQ + threadIdx.x; j < (q + 1) * F4PQ; j += 256) {
        const float4 pc4 = conf4[j];
        const int c0   = j * 4;
        const int idx0 = p * NCELL + c0;
        // 4 consecutive 4-aligned bits always live in one 32-bit word
        const unsigned mw = maskbits[idx0 >> 5] >> (idx0 & 31);
        const unsigned zw = zerobits[c0  >> 5] >> (c0  & 31);
        const float pc[4] = {pc4.x, pc4.y, pc4.z, pc4.w};
#pragma unroll
        for (int k = 0; k < 4; ++k) {
            if (!(((mw >> k) | (zw >> k)) & 1u)) {
                const float conf = sigmoidf_(pc[k]);
                sn += -(double)logf(1.0f - conf + 1e-12f);   // noobj BCE, t=0
                cn += 1.0;
            }
        }
    }

#pragma unroll
    for (int o = 32; o > 0; o >>= 1) {
        sn += __shfl_down(sn, o, 64);
        cn += __shfl_down(cn, o, 64);
    }
    __shared__ double sr[4][2];
    const int lane = threadIdx.x & 63, wid = threadIdx.x >> 6;
    if (lane == 0) { sr[wid][0] = sn; sr[wid][1] = cn; }
    __syncthreads();

    __shared__ bool amLast;
    if (threadIdx.x == 0) {
        partials[(size_t)blockIdx.x * 2 + 0] = sr[0][0] + sr[1][0] + sr[2][0] + sr[3][0];
        partials[(size_t)blockIdx.x * 2 + 1] = sr[0][1] + sr[1][1] + sr[2][1] + sr[3][1];
        __threadfence();                                   // release partials
        amLast = (atomicAdd(counter, 1) == NBLK_B - 1);
    }
    __syncthreads();
    if (!amLast) return;

    // last block: reduce partials (acquire via atomic+fence ordering)
    double psn = 0.0, pcn = 0.0;
    for (int r = threadIdx.x; r < NBLK_B; r += 256) {
        psn += partials[(size_t)r * 2 + 0];
        pcn += partials[(size_t)r * 2 + 1];
    }
#pragma unroll
    for (int o = 32; o > 0; o >>= 1) {
        psn += __shfl_down(psn, o, 64);
        pcn += __shfl_down(pcn, o, 64);
    }
    if (lane == 0) { sr[wid][0] = psn; sr[wid][1] = pcn; }
    __syncthreads();
    if (threadIdx.x == 0) {
        const double S = sr[0][0] + sr[1][0] + sr[2][0] + sr[3][0];
        const double C = sr[0][1] + sr[1][1] + sr[2][1] + sr[3][1];
        const double nm = fmax(sums[5], 1.0);     // max(sum(mask),1)
        const double nn = fmax(C, 1.0);           // max(sum(cm_false),1)
        const double lx = 2.0 * sums[0] / nm;     // XY_LOSS
        const double ly = 2.0 * sums[1] / nm;
        const double lw = 1.6 * sums[2] / nm;     // WH_LOSS
        const double lh = 1.6 * sums[3] / nm;
        const double lobj   = sums[4] / nm;       // OBJ_LOSS
        const double lnoobj = 0.5 * S / nn;       // NOOBJ_LOSS
        out[0] = (float)(lx + ly + lw + lh + lnoobj + lobj);
        out[1] = (float)lx;
        out[2] = (float)ly;
        out[3] = (float)lw;
        out[4] = (float)lh;
        out[5] = (float)lobj;
        out[6] = (float)lnoobj;
    }
}

// ---------------------------------------------------------------------------
extern "C" void kernel_launch(void* const* d_in, const int* in_sizes, int n_in,
                              void* d_out, int out_size, void* d_ws, size_t ws_size,
                              hipStream_t stream)
{
    const float* sample  = (const float*)d_in[0];   // (16,255,76,76) f32
    const float* targets = (const float*)d_in[1];   // (16,50,5) f32
    const float* anchors = (const float*)d_in[2];   // (3,2) f32
    float* out = (float*)d_out;                     // 7 f32

    char* ws = (char*)d_ws;
    unsigned* maskbits = (unsigned*)ws;                         // 8664 words
    unsigned* zerobits = (unsigned*)(ws + 34656);               // 181 words
    double*   sums     = (double*)(ws + 35392);                 // 6 doubles
    int*      counter  = (int*)(ws + 35392 + 64);
    double*   partials = (double*)(ws + 35392 + 128);           // 192*2 doubles

    yolo_prep<<<1, 1024, 0, stream>>>(sample, targets, anchors,
                                      maskbits, zerobits, sums, counter);
    yolo_noobj<<<NBLK_B, 256, 0, stream>>>(sample, maskbits, zerobits,
                                           sums, partials, counter, out);
}